// Round 5
// baseline (408.172 us; speedup 1.0000x reference)
//
#include <hip/hip_runtime.h>
#include <hip/hip_bf16.h>

typedef __bf16 bf16x8 __attribute__((ext_vector_type(8)));
typedef float floatx4 __attribute__((ext_vector_type(4)));
typedef unsigned short u16;

constexpr int T_DIM = 2048;
constexpr int H_DIM = 4096;
constexpr int O_DIM = 4096;
constexpr int R_DIM = 16;
constexpr int L_DIM = 32;
constexpr int NTILE = (T_DIM / 128) * (O_DIM / 128);  // 512 ticket slots

// ---------------- fp32 -> bf16 (RNE) ----------------
__device__ __forceinline__ u16 f2bf_rne(float f) {
  unsigned int u = __float_as_uint(f);
  u += 0x7fffu + ((u >> 16) & 1u);
  return (u16)(u >> 16);
}

// ---------------- fused convert: x, w, lora_a -> bf16 ----------------
__global__ __launch_bounds__(256) void cvt_all_kernel(const float4* __restrict__ x,
                                                      const float4* __restrict__ w,
                                                      const float4* __restrict__ a,
                                                      ushort4* __restrict__ xb,
                                                      ushort4* __restrict__ wb,
                                                      ushort4* __restrict__ ab) {
  const int NX = T_DIM * H_DIM / 4;
  const int NW = O_DIM * H_DIM / 4;
  const int NA = L_DIM * R_DIM * H_DIM / 4;
  int i = blockIdx.x * 256 + threadIdx.x;
  float4 v;
  ushort4* d;
  if (i < NX) { v = x[i]; d = xb + i; }
  else if (i < NX + NW) { v = w[i - NX]; d = wb + (i - NX); }
  else if (i < NX + NW + NA) { v = a[i - NX - NW]; d = ab + (i - NX - NW); }
  else return;
  ushort4 r;
  r.x = f2bf_rne(v.x); r.y = f2bf_rne(v.y); r.z = f2bf_rne(v.z); r.w = f2bf_rne(v.w);
  *d = r;
}

// ---------------- bucket: sort tokens by l (inactives last); zero shrunk + tickets ----------------
__global__ __launch_bounds__(256) void bucket_kernel(const int* __restrict__ idx,
                                                     int* __restrict__ offs,
                                                     int* __restrict__ list,
                                                     int* __restrict__ lof,
                                                     float* __restrict__ shrunk,
                                                     int* __restrict__ tickets) {
  __shared__ int cnt[L_DIM + 1];
  __shared__ int base_[L_DIM + 1];
  __shared__ int cur[L_DIM + 1];
  const int tid = threadIdx.x;
  float4 z = {0.f, 0.f, 0.f, 0.f};
  float4* s4 = (float4*)shrunk;
  for (int i = tid; i < T_DIM * R_DIM / 4; i += 256) s4[i] = z;
  for (int i = tid; i < NTILE; i += 256) tickets[i] = 0;
  if (tid <= L_DIM) cnt[tid] = 0;
  __syncthreads();
  for (int t = tid; t < T_DIM; t += 256) {
    int l = idx[t];
    atomicAdd(&cnt[l >= 0 ? l : L_DIM], 1);
  }
  __syncthreads();
  if (tid == 0) {
    int acc = 0;
    for (int l = 0; l <= L_DIM; ++l) { base_[l] = acc; acc += cnt[l]; }
  }
  __syncthreads();
  if (tid <= L_DIM) {
    cur[tid] = 0;
    offs[tid] = base_[tid];  // offs[32] = #active tokens
  }
  __syncthreads();
  for (int t = tid; t < T_DIM; t += 256) {
    int l = idx[t];
    int b = l >= 0 ? l : L_DIM;
    int p = base_[b] + atomicAdd(&cur[b], 1);
    list[p] = t;
    lof[p] = l >= 0 ? l : 0;  // shrunk row is zero for inactives -> lora adds 0
  }
}

// ---------------- MFMA shrink -> PERMUTED shrunk: shrunk_p[p, r] += x[list[p], kq] . A[l, r, kq] ----------------
__global__ __launch_bounds__(256) void lora_shrink_mfma(const u16* __restrict__ xb,
                                                        const u16* __restrict__ ab,
                                                        const int* __restrict__ offs,
                                                        const int* __restrict__ list,
                                                        float* __restrict__ shrunk) {
  const int l = blockIdx.x;
  const int kbase = blockIdx.y * (H_DIM / 4);
  const int off = offs[l];
  const int n = offs[l + 1] - off;
  if (n == 0) return;
  const int wave = threadIdx.x >> 6, lane = threadIdx.x & 63;
  const int quad = lane >> 4, mn = lane & 15;
  const int ngroups = (n + 15) / 16;
  const u16* arow = ab + ((long)l * R_DIM + mn) * H_DIM + quad * 8 + kbase;  // r = mn

  for (int g = wave; g < ngroups; g += 4) {
    int p = off + g * 16 + mn;
    int pc = off + n - 1;
    int tok = list[p < pc ? p : pc];
    const u16* xrow = xb + (long)tok * H_DIM + quad * 8 + kbase;
    floatx4 acc = {0.f, 0.f, 0.f, 0.f};
#pragma unroll 4
    for (int k = 0; k < H_DIM / 4; k += 32) {
      bf16x8 xf = *(const bf16x8*)(xrow + k);
      bf16x8 af = *(const bf16x8*)(arow + k);
      acc = __builtin_amdgcn_mfma_f32_16x16x32_bf16(xf, af, acc, 0, 0, 0);
    }
#pragma unroll
    for (int r = 0; r < 4; ++r) {
      int trow = g * 16 + quad * 4 + r;
      if (trow < n) atomicAdd(&shrunk[(off + trow) * R_DIM + mn], acc[r]);  // permuted row
    }
  }
}

// ---------------- async 16B global->LDS ----------------
__device__ __forceinline__ void async16(const u16* g, char* l) {
  __builtin_amdgcn_global_load_lds((const __attribute__((address_space(1))) unsigned int*)g,
                                   (__attribute__((address_space(3))) unsigned int*)l,
                                   16, 0, 0);
}

// ---------------- bf16 MFMA GEMM, split-K=2, permuted rows, ticket-fused epilogue ----------------
// z=0 partial -> out (token rows), z=1 partial -> part1 (token rows). Second arrival per
// tile (device-scope ticket) reads the other partial and finalizes (+bias, +shrunk.B[l]).
__global__ __launch_bounds__(256) void gemm_fused_kernel(
    const u16* __restrict__ Abf, const u16* __restrict__ Bbf,
    float* __restrict__ outp, float* __restrict__ part1,
    const int* __restrict__ list, const int* __restrict__ lof,
    const float* __restrict__ shrunk, const float* __restrict__ bias,
    const float* __restrict__ lora_b, int* __restrict__ tickets, int klen) {
  __shared__ __align__(16) char lds[2 * 128 * 32 * 2];
  char* ldsA = lds;
  char* ldsB = lds + 128 * 32 * 2;

  const int tid = threadIdx.x;
  const int lane = tid & 63;
  const int wave = tid >> 6;
  const int wr = wave >> 1, wc = wave & 1;
  const int quad = lane >> 4, mn = lane & 15;

  const int t0 = blockIdx.y * 128;  // permuted token base
  const int o0 = blockIdx.x * 128;
  const int kbase = blockIdx.z * klen;

  // A staging gathers permuted rows via list (source addrs may be per-lane;
  // only the LDS dest must be base + lane*16, which it is).
  const int j0 = tid, j1 = tid + 256;
  const int tokA0 = list[t0 + (j0 >> 2)];
  const int tokA1 = list[t0 + (j1 >> 2)];
  const u16* gA0 = Abf + (long)tokA0 * H_DIM + (j0 & 3) * 8 + kbase;
  const u16* gA1 = Abf + (long)tokA1 * H_DIM + (j1 & 3) * 8 + kbase;
  const u16* gB0 = Bbf + (long)(o0 + (j0 >> 2)) * H_DIM + (j0 & 3) * 8 + kbase;
  const u16* gB1 = Bbf + (long)(o0 + (j1 >> 2)) * H_DIM + (j1 & 3) * 8 + kbase;
  char* lA0 = ldsA + j0 * 16;
  char* lA1 = ldsA + j1 * 16;
  char* lB0 = ldsB + j0 * 16;
  char* lB1 = ldsB + j1 * 16;

  const char* apA[4];
  const char* apB[4];
#pragma unroll
  for (int i = 0; i < 4; ++i) {
    apA[i] = ldsA + ((wr * 64 + i * 16 + mn) * 32 + quad * 8) * 2;
    apB[i] = ldsB + ((wc * 64 + i * 16 + mn) * 32 + quad * 8) * 2;
  }

  floatx4 acc[4][4] = {};

  for (int k0 = 0; k0 < klen; k0 += 32) {
    __syncthreads();
    async16(gA0 + k0, lA0);
    async16(gA1 + k0, lA1);
    async16(gB0 + k0, lB0);
    async16(gB1 + k0, lB1);
    __syncthreads();

    bf16x8 af[4], bfr[4];
#pragma unroll
    for (int i = 0; i < 4; ++i) {
      af[i] = *(const bf16x8*)apA[i];
      bfr[i] = *(const bf16x8*)apB[i];
    }
#pragma unroll
    for (int i = 0; i < 4; ++i)
#pragma unroll
      for (int nn = 0; nn < 4; ++nn)
        acc[i][nn] = __builtin_amdgcn_mfma_f32_16x16x32_bf16(af[i], bfr[nn], acc[i][nn], 0, 0, 0);
  }

  // Token per C row (C/D layout: col = lane&15, row = quad*4 + reg).
  int tok[4][4];
#pragma unroll
  for (int i = 0; i < 4; ++i)
#pragma unroll
    for (int r = 0; r < 4; ++r) tok[i][r] = list[t0 + wr * 64 + i * 16 + quad * 4 + r];

  // 1) write own partial (token-row space; regions disjoint per tile)
  float* own = blockIdx.z ? part1 : outp;
#pragma unroll
  for (int i = 0; i < 4; ++i)
#pragma unroll
    for (int r = 0; r < 4; ++r) {
      float* prow = own + (long)tok[i][r] * O_DIM + o0 + wc * 64;
#pragma unroll
      for (int nn = 0; nn < 4; ++nn) prow[nn * 16 + mn] = acc[i][nn][r];
    }

  // 2) ticket: second arrival finalizes (no spinning -> no dispatch-order assumption)
  __shared__ int tk;
  __syncthreads();
  if (tid == 0) {
    __threadfence();  // release own partial to device scope
    tk = atomicAdd(&tickets[blockIdx.y * gridDim.x + blockIdx.x], 1);
  }
  __syncthreads();
  if (tk == 0) return;
  __threadfence();  // acquire other block's partial

  // 3) base finalize: out = own acc + other partial + bias
  const float* oth = blockIdx.z ? outp : part1;
  float bv[4];
#pragma unroll
  for (int nn = 0; nn < 4; ++nn) bv[nn] = bias[o0 + wc * 64 + nn * 16 + mn];
#pragma unroll
  for (int i = 0; i < 4; ++i)
#pragma unroll
    for (int r = 0; r < 4; ++r) {
      const float* prow = oth + (long)tok[i][r] * O_DIM + o0 + wc * 64;
      float* orow = outp + (long)tok[i][r] * O_DIM + o0 + wc * 64;
#pragma unroll
      for (int nn = 0; nn < 4; ++nn)
        orow[nn * 16 + mn] = acc[i][nn][r] + prow[nn * 16 + mn] + bv[nn];
    }

  // 4) LoRA expand: rows sorted by l => B[l] regs reloaded rarely
  int lcur = -1;
  float4 B[4][4];  // [nn][q]: B[l][o(nn)][q*4..q*4+3]
#pragma unroll
  for (int i = 0; i < 4; ++i) {
#pragma unroll
    for (int r = 0; r < 4; ++r) {
      const int pt = t0 + wr * 64 + i * 16 + quad * 4 + r;
      const int l = lof[pt];
      if (l != lcur) {
        lcur = l;
#pragma unroll
        for (int nn = 0; nn < 4; ++nn) {
          const float4* bg = (const float4*)(lora_b + ((long)l * O_DIM + o0 + wc * 64 + nn * 16 + mn) * R_DIM);
#pragma unroll
          for (int q = 0; q < 4; ++q) B[nn][q] = bg[q];
        }
      }
      const float4* sp = (const float4*)(shrunk + pt * R_DIM);  // permuted, L2-hot
      float4 s0 = sp[0], s1 = sp[1], s2 = sp[2], s3 = sp[3];
      float* orow = outp + (long)tok[i][r] * O_DIM + o0 + wc * 64;
#pragma unroll
      for (int nn = 0; nn < 4; ++nn) {
        float d = s0.x * B[nn][0].x + s0.y * B[nn][0].y + s0.z * B[nn][0].z + s0.w * B[nn][0].w;
        d += s1.x * B[nn][1].x + s1.y * B[nn][1].y + s1.z * B[nn][1].z + s1.w * B[nn][1].w;
        d += s2.x * B[nn][2].x + s2.y * B[nn][2].y + s2.z * B[nn][2].z + s2.w * B[nn][2].w;
        d += s3.x * B[nn][3].x + s3.y * B[nn][3].y + s3.z * B[nn][3].z + s3.w * B[nn][3].w;
        orow[nn * 16 + mn] += d;
      }
    }
  }
}

extern "C" void kernel_launch(void* const* d_in, const int* in_sizes, int n_in,
                              void* d_out, int out_size, void* d_ws, size_t ws_size,
                              hipStream_t stream) {
  (void)in_sizes; (void)n_in; (void)out_size; (void)ws_size;
  const float* x      = (const float*)d_in[0];
  const float* w      = (const float*)d_in[1];
  const float* bias   = (const float*)d_in[2];
  const float* lora_a = (const float*)d_in[3];
  const float* lora_b = (const float*)d_in[4];
  const int*   idx    = (const int*)d_in[5];
  float* out = (float*)d_out;

  char* ws = (char*)d_ws;
  const size_t OFF_XB = 0;                               // 16 MiB  x bf16
  const size_t OFF_WB = (size_t)16 << 20;                // 32 MiB  w bf16
  const size_t OFF_SHRUNK = (size_t)48 << 20;            // 128 KiB (permuted)
  const size_t OFF_LIST = OFF_SHRUNK + 131072;           // 8 KiB
  const size_t OFF_LOF  = OFF_LIST + 8192;               // 8 KiB
  const size_t OFF_OFFS = OFF_LOF + 8192;                // 136 B
  const size_t OFF_TICK = OFF_OFFS + 256;                // 2 KiB
  const size_t OFF_PART = (size_t)49 << 20;              // 32 MiB fp32 partial1
  // lora_a bf16 (4 MiB) overlaid on partial1: written by cvt, consumed by shrink,
  // then clobbered by gemm partial stores — safe under stream ordering. Total 81 MiB
  // (proven available in R2-R4).
  const size_t OFF_AB = OFF_PART;

  u16* xb = (u16*)(ws + OFF_XB);
  u16* wb = (u16*)(ws + OFF_WB);
  u16* ab = (u16*)(ws + OFF_AB);
  float* shrunk = (float*)(ws + OFF_SHRUNK);
  int* list = (int*)(ws + OFF_LIST);
  int* lof = (int*)(ws + OFF_LOF);
  int* offs = (int*)(ws + OFF_OFFS);
  int* tickets = (int*)(ws + OFF_TICK);
  float* part1 = (float*)(ws + OFF_PART);

  const int NCVT = (T_DIM * H_DIM + O_DIM * H_DIM + L_DIM * R_DIM * H_DIM) / 4;
  cvt_all_kernel<<<NCVT / 256, 256, 0, stream>>>((const float4*)x, (const float4*)w,
                                                 (const float4*)lora_a,
                                                 (ushort4*)xb, (ushort4*)wb, (ushort4*)ab);
  bucket_kernel<<<1, 256, 0, stream>>>(idx, offs, list, lof, shrunk, tickets);
  lora_shrink_mfma<<<dim3(L_DIM, 4), 256, 0, stream>>>(xb, ab, offs, list, shrunk);

  dim3 grid(O_DIM / 128, T_DIM / 128, 2);
  gemm_fused_kernel<<<grid, 256, 0, stream>>>(xb, wb, out, part1, list, lof, shrunk,
                                              bias, lora_b, tickets, H_DIM / 2);
}

// Round 6
// 287.443 us; speedup vs baseline: 1.4200x; 1.4200x over previous
//
#include <hip/hip_runtime.h>
#include <hip/hip_bf16.h>

typedef __bf16 bf16x8 __attribute__((ext_vector_type(8)));
typedef float floatx4 __attribute__((ext_vector_type(4)));
typedef unsigned short u16;

constexpr int T_DIM = 2048;
constexpr int H_DIM = 4096;
constexpr int O_DIM = 4096;
constexpr int R_DIM = 16;
constexpr int L_DIM = 32;
constexpr int GSZ = 8;  // tokens per epilogue block

constexpr int NX4 = T_DIM * H_DIM / 4;
constexpr int NW4 = O_DIM * H_DIM / 4;
constexpr int NA4 = L_DIM * R_DIM * H_DIM / 4;
constexpr int NCVT_BLK = (NX4 + NW4 + NA4) / 256;   // 26624
constexpr int NZERO_BLK = (T_DIM * R_DIM / 4) / 256; // 32

// ---------------- fp32 -> bf16 (RNE) ----------------
__device__ __forceinline__ u16 f2bf_rne(float f) {
  unsigned int u = __float_as_uint(f);
  u += 0x7fffu + ((u >> 16) & 1u);
  return (u16)(u >> 16);
}

// ---------------- pre: convert x/w/lora_a -> bf16, bucket tokens, zero shrunk ----------------
__global__ __launch_bounds__(256) void pre_kernel(const float4* __restrict__ x,
                                                  const float4* __restrict__ w,
                                                  const float4* __restrict__ a,
                                                  ushort4* __restrict__ xb,
                                                  ushort4* __restrict__ wb,
                                                  ushort4* __restrict__ ab,
                                                  const int* __restrict__ idx,
                                                  int* __restrict__ offs,
                                                  int* __restrict__ list,
                                                  float* __restrict__ shrunk) {
  const int bid = blockIdx.x;
  const int tid = threadIdx.x;
  if (bid < NCVT_BLK) {
    int i = bid * 256 + tid;
    float4 v;
    ushort4* d;
    if (i < NX4) { v = x[i]; d = xb + i; }
    else if (i < NX4 + NW4) { v = w[i - NX4]; d = wb + (i - NX4); }
    else { v = a[i - NX4 - NW4]; d = ab + (i - NX4 - NW4); }
    ushort4 r;
    r.x = f2bf_rne(v.x); r.y = f2bf_rne(v.y); r.z = f2bf_rne(v.z); r.w = f2bf_rne(v.w);
    *d = r;
    return;
  }
  if (bid > NCVT_BLK) {
    // zero shrunk
    int i = (bid - NCVT_BLK - 1) * 256 + tid;
    float4 z = {0.f, 0.f, 0.f, 0.f};
    ((float4*)shrunk)[i] = z;
    return;
  }
  // bucket block: sort tokens by l (inactives last)
  __shared__ int cnt[L_DIM + 1];
  __shared__ int base_[L_DIM + 1];
  __shared__ int cur[L_DIM + 1];
  if (tid <= L_DIM) cnt[tid] = 0;
  __syncthreads();
  for (int t = tid; t < T_DIM; t += 256) {
    int l = idx[t];
    atomicAdd(&cnt[l >= 0 ? l : L_DIM], 1);
  }
  __syncthreads();
  if (tid == 0) {
    int acc = 0;
    for (int l = 0; l <= L_DIM; ++l) { base_[l] = acc; acc += cnt[l]; }
  }
  __syncthreads();
  if (tid <= L_DIM) {
    cur[tid] = 0;
    offs[tid] = base_[tid];  // offs[32] = #active tokens
  }
  __syncthreads();
  for (int t = tid; t < T_DIM; t += 256) {
    int l = idx[t];
    int b = l >= 0 ? l : L_DIM;
    int p = base_[b] + atomicAdd(&cur[b], 1);
    list[p] = t;
  }
}

// ---------------- MFMA shrink, split-K: shrunk[tok, r] += x[tok, kq] . A[l, r, kq] ----------------
__global__ __launch_bounds__(256) void lora_shrink_mfma(const u16* __restrict__ xb,
                                                        const u16* __restrict__ ab,
                                                        const int* __restrict__ offs,
                                                        const int* __restrict__ list,
                                                        float* __restrict__ shrunk) {
  const int l = blockIdx.x;
  const int kbase = blockIdx.y * (H_DIM / 4);
  const int off = offs[l];
  const int n = offs[l + 1] - off;
  if (n == 0) return;
  const int wave = threadIdx.x >> 6, lane = threadIdx.x & 63;
  const int quad = lane >> 4, mn = lane & 15;
  const int ngroups = (n + 15) / 16;
  const u16* arow = ab + ((long)l * R_DIM + mn) * H_DIM + quad * 8 + kbase;  // r = mn

  for (int g = wave; g < ngroups; g += 4) {
    int p = off + g * 16 + mn;
    int pc = off + n - 1;
    int tok = list[p < pc ? p : pc];  // clamp for partial groups
    const u16* xrow = xb + (long)tok * H_DIM + quad * 8 + kbase;
    floatx4 acc = {0.f, 0.f, 0.f, 0.f};
#pragma unroll 8
    for (int k = 0; k < H_DIM / 4; k += 32) {
      bf16x8 xf = *(const bf16x8*)(xrow + k);
      bf16x8 af = *(const bf16x8*)(arow + k);
      acc = __builtin_amdgcn_mfma_f32_16x16x32_bf16(xf, af, acc, 0, 0, 0);
    }
#pragma unroll
    for (int r = 0; r < 4; ++r) {
      int trow = g * 16 + quad * 4 + r;
      if (trow < n) atomicAdd(&shrunk[list[off + trow] * R_DIM + mn], acc[r]);
    }
  }
}

// ---------------- async 16B global->LDS ----------------
__device__ __forceinline__ void async16(const u16* g, char* l) {
  __builtin_amdgcn_global_load_lds((const __attribute__((address_space(1))) unsigned int*)g,
                                   (__attribute__((address_space(3))) unsigned int*)l,
                                   16, 0, 0);
}

// ---------------- bf16 MFMA GEMM (B^T), split-K=2, fp32 partials (R2/R4 proven config) ----------------
__global__ __launch_bounds__(256) void gemm_kernel(const u16* __restrict__ Abf,
                                                   const u16* __restrict__ Bbf,
                                                   float* __restrict__ dest0,
                                                   float* __restrict__ dest1,
                                                   int klen) {
  __shared__ __align__(16) char lds[2 * 128 * 32 * 2];
  char* ldsA = lds;
  char* ldsB = lds + 128 * 32 * 2;

  const int tid = threadIdx.x;
  const int lane = tid & 63;
  const int wave = tid >> 6;
  const int wr = wave >> 1, wc = wave & 1;
  const int quad = lane >> 4, mn = lane & 15;

  const int t0 = blockIdx.y * 128;
  const int o0 = blockIdx.x * 128;
  const int kbase = blockIdx.z * klen;
  float* dest = blockIdx.z ? dest1 : dest0;

  const int j0 = tid, j1 = tid + 256;
  const u16* gA0 = Abf + (long)(t0 + (j0 >> 2)) * H_DIM + (j0 & 3) * 8 + kbase;
  const u16* gA1 = Abf + (long)(t0 + (j1 >> 2)) * H_DIM + (j1 & 3) * 8 + kbase;
  const u16* gB0 = Bbf + (long)(o0 + (j0 >> 2)) * H_DIM + (j0 & 3) * 8 + kbase;
  const u16* gB1 = Bbf + (long)(o0 + (j1 >> 2)) * H_DIM + (j1 & 3) * 8 + kbase;
  char* lA0 = ldsA + j0 * 16;
  char* lA1 = ldsA + j1 * 16;
  char* lB0 = ldsB + j0 * 16;
  char* lB1 = ldsB + j1 * 16;

  const char* apA[4];
  const char* apB[4];
#pragma unroll
  for (int i = 0; i < 4; ++i) {
    apA[i] = ldsA + ((wr * 64 + i * 16 + mn) * 32 + quad * 8) * 2;
    apB[i] = ldsB + ((wc * 64 + i * 16 + mn) * 32 + quad * 8) * 2;
  }

  floatx4 acc[4][4] = {};

  for (int k0 = 0; k0 < klen; k0 += 32) {
    __syncthreads();
    async16(gA0 + k0, lA0);
    async16(gA1 + k0, lA1);
    async16(gB0 + k0, lB0);
    async16(gB1 + k0, lB1);
    __syncthreads();

    bf16x8 af[4], bfr[4];
#pragma unroll
    for (int i = 0; i < 4; ++i) {
      af[i] = *(const bf16x8*)apA[i];
      bfr[i] = *(const bf16x8*)apB[i];
    }
#pragma unroll
    for (int i = 0; i < 4; ++i)
#pragma unroll
      for (int nn = 0; nn < 4; ++nn)
        acc[i][nn] = __builtin_amdgcn_mfma_f32_16x16x32_bf16(af[i], bfr[nn], acc[i][nn], 0, 0, 0);
  }

  // C/D layout: col = lane&15, row = quad*4 + reg
#pragma unroll
  for (int i = 0; i < 4; ++i) {
#pragma unroll
    for (int r = 0; r < 4; ++r) {
      const int t = t0 + wr * 64 + i * 16 + quad * 4 + r;
      float* orow = dest + (long)t * O_DIM;
#pragma unroll
      for (int nn = 0; nn < 4; ++nn)
        orow[o0 + wc * 64 + nn * 16 + mn] = acc[i][nn][r];
    }
  }
}

// ---------------- epilogue v3: token-grouped, B cached in regs, prefetched token ids ----------------
// block = (o-chunk of 1024, group of GSZ tokens from sorted list). Token id and lora
// index for all GSZ tokens loaded up-front (breaks the serial scalar-load chain).
// B[l] reload branch is block-uniform (t uniform per iteration).
__global__ __launch_bounds__(256) void epilogue_kernel(float* __restrict__ out,
                                                       const float* __restrict__ part1,
                                                       const float* __restrict__ bias,
                                                       const float* __restrict__ shrunk,
                                                       const float* __restrict__ lora_b,
                                                       const int* __restrict__ idx,
                                                       const int* __restrict__ list) {
  const int o = blockIdx.x * 1024 + threadIdx.x * 4;
  const int g0 = blockIdx.y * GSZ;

  int ts[GSZ], ls[GSZ];
#pragma unroll
  for (int gi = 0; gi < GSZ; ++gi) ts[gi] = list[g0 + gi];
#pragma unroll
  for (int gi = 0; gi < GSZ; ++gi) {
    int l = idx[ts[gi]];
    ls[gi] = l < 0 ? 0 : l;  // shrunk row is zero when l<0 -> dot = 0
  }

  float4 bv = *(const float4*)(bias + o);
  float4 B[4][4];
  int lcur = -1;
#pragma unroll
  for (int gi = 0; gi < GSZ; ++gi) {
    const int t = ts[gi];
    if (ls[gi] != lcur) {  // block-uniform branch
      lcur = ls[gi];
      const float4* bg = (const float4*)(lora_b + ((long)lcur * O_DIM + o) * R_DIM);
#pragma unroll
      for (int j = 0; j < 4; ++j)
#pragma unroll
        for (int q = 0; q < 4; ++q) B[j][q] = bg[j * 4 + q];
    }
    const float4* sp = (const float4*)(shrunk + t * R_DIM);
    float4 s0 = sp[0], s1 = sp[1], s2 = sp[2], s3 = sp[3];
    float4 v = *(const float4*)(out + (long)t * O_DIM + o);
    float4 p = *(const float4*)(part1 + (long)t * O_DIM + o);
    v.x += p.x + bv.x; v.y += p.y + bv.y; v.z += p.z + bv.z; v.w += p.w + bv.w;
    float* vp = &v.x;
#pragma unroll
    for (int j = 0; j < 4; ++j) {
      float d = s0.x * B[j][0].x + s0.y * B[j][0].y + s0.z * B[j][0].z + s0.w * B[j][0].w;
      d += s1.x * B[j][1].x + s1.y * B[j][1].y + s1.z * B[j][1].z + s1.w * B[j][1].w;
      d += s2.x * B[j][2].x + s2.y * B[j][2].y + s2.z * B[j][2].z + s2.w * B[j][2].w;
      d += s3.x * B[j][3].x + s3.y * B[j][3].y + s3.z * B[j][3].z + s3.w * B[j][3].w;
      vp[j] += d;
    }
    *(float4*)(out + (long)t * O_DIM + o) = v;
  }
}

extern "C" void kernel_launch(void* const* d_in, const int* in_sizes, int n_in,
                              void* d_out, int out_size, void* d_ws, size_t ws_size,
                              hipStream_t stream) {
  (void)in_sizes; (void)n_in; (void)out_size; (void)ws_size;
  const float* x      = (const float*)d_in[0];
  const float* w      = (const float*)d_in[1];
  const float* bias   = (const float*)d_in[2];
  const float* lora_a = (const float*)d_in[3];
  const float* lora_b = (const float*)d_in[4];
  const int*   idx    = (const int*)d_in[5];
  float* out = (float*)d_out;

  char* ws = (char*)d_ws;
  const size_t OFF_XB = 0;                               // 16 MiB  x bf16
  const size_t OFF_WB = (size_t)16 << 20;                // 32 MiB  w bf16
  const size_t OFF_SHRUNK = (size_t)48 << 20;            // 128 KiB
  const size_t OFF_LIST = OFF_SHRUNK + 131072;           // 8 KiB
  const size_t OFF_OFFS = OFF_LIST + 8192;               // 136 B
  const size_t OFF_PART = (size_t)49 << 20;              // 32 MiB fp32 partial1
  // lora_a bf16 (4 MiB) overlaid on partial1: written by pre, consumed by shrink,
  // then clobbered by gemm partial stores — safe under stream ordering. Total 81 MiB
  // (proven available R2-R5).
  const size_t OFF_AB = OFF_PART;

  u16* xb = (u16*)(ws + OFF_XB);
  u16* wb = (u16*)(ws + OFF_WB);
  u16* ab = (u16*)(ws + OFF_AB);
  float* shrunk = (float*)(ws + OFF_SHRUNK);
  int* list = (int*)(ws + OFF_LIST);
  int* offs = (int*)(ws + OFF_OFFS);
  float* part1 = (float*)(ws + OFF_PART);

  pre_kernel<<<NCVT_BLK + 1 + NZERO_BLK, 256, 0, stream>>>(
      (const float4*)x, (const float4*)w, (const float4*)lora_a,
      (ushort4*)xb, (ushort4*)wb, (ushort4*)ab, idx, offs, list, shrunk);

  lora_shrink_mfma<<<dim3(L_DIM, 4), 256, 0, stream>>>(xb, ab, offs, list, shrunk);

  dim3 grid(O_DIM / 128, T_DIM / 128, 2);
  gemm_kernel<<<grid, 256, 0, stream>>>(xb, wb, out, part1, H_DIM / 2);

  dim3 egrid(O_DIM / 1024, T_DIM / GSZ);
  epilogue_kernel<<<egrid, 256, 0, stream>>>(out, part1, bias, shrunk, lora_b, idx, list);
}